// Round 9
// baseline (308.651 us; speedup 1.0000x reference)
//
#include <hip/hip_runtime.h>
#include <hip/hip_bf16.h>

// KNN_itc: out[b][n] = sum over support descriptors m (441) of top-3 (over 441
// query descriptors) cosine similarities, C=640, bf16 MFMA.
//
// R14 (vs R13 = 256us total, gemm 113.6us):
//  - prep UNCHANGED from R13 (fused norm+pack, 2 dispatches total). Six rounds
//    of prep restructuring left the non-gemm ~140us constant -> harness-fixed
//    cost; prep itself ~10-20us. All remaining leverage is in the gemm.
//  - gemm: K-loop is L2-BW-bound: 44KB/kt/block (28 A + 4x4=16 B redundant
//    inter-wave) = 88KB/kt/CU ~ 1570cy vs 272cy MFMA. Fix: B through LDS,
//    barrier-LIGHT: stage all 40 B chunks of a 10-kt super-phase (40KB) once
//    via global_load_lds, 2 phases => 4 barriers total (R6's 20 barriers was
//    the regression; R12's 4x B redundancy is the traffic). A stays
//    direct-to-register (zero intra-block reuse). B frags via lane-linear
//    ds_read_b128 (conflict-free). Traffic 44 -> 32 KB/kt/block (-27%).
//  - predicted gemm ~88-98us; if unchanged -> issue-bound, revise; if
//    regressed -> revert to R12 gemm (structure ceiling ~113).

#define B_IMGS 75
#define N_CLS  5
#define C_DIM  640
#define HW     441
#define HWP    448
#define NKT    20            // 640 / 32 k-chunks
#define NRB    28            // 448 / 16 row-blocks per image
#define CHUNK  512           // 16 rows x 32 k elems = 1 KiB

typedef __attribute__((ext_vector_type(8))) short  short8;   // 8 x bf16
typedef __attribute__((ext_vector_type(4))) float  float4v;  // MFMA acc

__device__ __forceinline__ void ins3(float& t0, float& t1, float& t2, float v) {
    float m  = fminf(t0, v);
    t0 = fmaxf(t0, v);
    float m2 = fminf(t1, m);
    t1 = fmaxf(t1, m);
    t2 = fmaxf(t2, m2);
}

__device__ __forceinline__ void glds16(const __hip_bfloat16* g, __hip_bfloat16* l) {
    __builtin_amdgcn_global_load_lds(
        (const __attribute__((address_space(1))) unsigned int*)g,
        (__attribute__((address_space(3))) unsigned int*)l, 16, 0, 0);
}

// ---- fused prep: sumsq + normalize + bf16 + fragment-linear pack ----
// block=(img 0..79, h0 0..6); 560 blocks x 256 thr
// chunk layout: elem(row=r16, k32) at oct*128 + r16*8 + (k32&7), oct=k32>>3
//   -> gemm lane l reads elems [l*8, l*8+8): row=l&15, k32=(l>>4)*8+j (MFMA frag)
__global__ __launch_bounds__(256)
void prep_kernel(const float* __restrict__ q, const float* __restrict__ S,
                 __hip_bfloat16* __restrict__ qn2, __hip_bfloat16* __restrict__ sn2,
                 float* __restrict__ out) {
    __shared__ float part[4][64];
    __shared__ float inv[64];

    int bid = blockIdx.x;
    // zero the output accumulator (replaces the hipMemsetAsync dispatch);
    // gemm is a later dispatch on the same stream -> ordering is safe.
    if (bid == 0) {
        for (int i = threadIdx.x; i < B_IMGS * N_CLS; i += 256) out[i] = 0.f;
    }

    int img = bid / 7;               // 0..79 (0..74 = q, 75..79 = S)
    int h0  = bid % 7;
    const float* src; __hip_bfloat16* dst;
    if (img < B_IMGS) {
        src = q + (size_t)img * C_DIM * HW;
        dst = qn2 + (size_t)img * NRB * NKT * CHUNK;
    } else {
        src = S + (size_t)(img - B_IMGS) * C_DIM * HW;
        dst = sn2 + (size_t)(img - B_IMGS) * NRB * NKT * CHUNK;
    }
    int t  = threadIdx.x;
    int hl = t & 63;
    int p  = t >> 6;                 // wave id / 160-channel slice
    int hw = h0 * 64 + hl;
    int hwc = (hw < HW) ? hw : (HW - 1);

    // ---- pass 1: sum of squares over C (coalesced, 16-deep batches) ----
    float ss = 0.f;
    for (int c0 = p * 160; c0 < (p + 1) * 160; c0 += 16) {
        float v[16];
#pragma unroll
        for (int j = 0; j < 16; ++j) v[j] = src[(size_t)(c0 + j) * HW + hwc];
#pragma unroll
        for (int j = 0; j < 16; ++j) ss += v[j] * v[j];
    }
    part[p][hl] = ss;
    __syncthreads();
    if (t < 64) {
        float tot = part[0][t] + part[1][t] + part[2][t] + part[3][t];
        // pad rows (hw>=441) -> 0 so packed pad descriptors are zeros
        inv[t] = (h0 * 64 + t < HW) ? rsqrtf(tot) : 0.f;
    }
    __syncthreads();

    // ---- pass 2: L2/L3-hot re-read, scale, pack in registers, store ----
    // wave p owns chunk rb = h0*4+p; lane tl writes bytes [tl*16, tl*16+16)
    int tl  = hl;
    int row = tl & 15;
    int oct = tl >> 4;
    int rb  = h0 * 4 + p;
    int hw2 = h0 * 64 + p * 16 + row;
    int hw2c = (hw2 < HW) ? hw2 : (HW - 1);
    float iv = inv[p * 16 + row];    // 0 for pad rows
    const float* s2 = src + hw2c;
#pragma unroll 2
    for (int kt = 0; kt < NKT; ++kt) {
        float v[8];
#pragma unroll
        for (int j = 0; j < 8; ++j)
            v[j] = s2[(size_t)(kt * 32 + oct * 8 + j) * HW];
        short8 o;
#pragma unroll
        for (int j = 0; j < 8; ++j) {
            __hip_bfloat16 h = __float2bfloat16(v[j] * iv);
            o[j] = *(short*)&h;
        }
        *(short8*)(dst + ((size_t)rb * NKT + kt) * CHUNK + tl * 8) = o;
    }
}

// ---- gemm + fused top-3: A direct-to-reg, B via 2-phase LDS (4 barriers) ----
#define LOADA(aS, kt)                                                           \
    {                                                                           \
        _Pragma("unroll")                                                       \
        for (int r = 0; r < 7; ++r)                                             \
            aS[r] = *(const short8*)(pA + ((size_t)(r * 4 + w) * NKT + (kt)) * CHUNK); \
    }

#define BREAD(bS, k10)                                                          \
    {                                                                           \
        _Pragma("unroll")                                                       \
        for (int j = 0; j < 4; ++j)                                             \
            bS[j] = *(const short8*)(sbuf + ((k10) * 4 + j) * CHUNK + lane * 8);\
    }

#define MFMASET(aS, bS)                                                         \
    {                                                                           \
        _Pragma("unroll")                                                       \
        for (int r = 0; r < 7; ++r)                                             \
            _Pragma("unroll")                                                   \
            for (int j = 0; j < 4; ++j)                                         \
                acc[r][j] = __builtin_amdgcn_mfma_f32_16x16x32_bf16(            \
                    aS[r], bS[j], acc[r][j], 0, 0, 0);                          \
    }

__global__ __launch_bounds__(256, 2)
void gemm_top3_kernel(const __hip_bfloat16* __restrict__ qn2,
                      const __hip_bfloat16* __restrict__ sn2,
                      float* __restrict__ out) {
    __shared__ __hip_bfloat16 sbuf[40 * CHUNK];   // 40 KiB: B chunks [kt10][jb]
    __shared__ float mrg[4][64][3];

    // XCD-grouping swizzle: all 35 (n,mt) blocks of image b on one XCD
    int id  = blockIdx.x;
    int xcd = id & 7;
    int j8  = id >> 3;
    int b   = (j8 / 35) * 8 + xcd;
    if (b >= B_IMGS) return;
    int inner = j8 % 35;
    int n  = inner / 7;
    int mt = inner % 7;

    int tid  = threadIdx.x;
    int w    = tid >> 6;
    int lane = tid & 63;
    int c16  = lane & 15;
    int quad = lane >> 4;

    // A fragment base: lane l owns bytes [l*16, l*16+16) of each 1KiB chunk
    const __hip_bfloat16* pA  = qn2 + (size_t)b * NRB * NKT * CHUNK + lane * 8;
    const __hip_bfloat16* qBb = sn2 + ((size_t)n * NRB + mt * 4) * NKT * CHUNK;

    float4v acc[7][4];
#pragma unroll
    for (int r = 0; r < 7; ++r)
#pragma unroll
        for (int j = 0; j < 4; ++j)
            acc[r][j] = (float4v){0.f, 0.f, 0.f, 0.f};

    short8 a0[7], a1[7], bb0[4], bb1[4];

    for (int ph = 0; ph < 2; ++ph) {
        __syncthreads();   // phase-0: no-op cost; phase-1: all B reads done
        // stage 40 B chunks (10 kt x 4 jb); wave w moves chunks [w*10, w*10+10)
#pragma unroll
        for (int i = 0; i < 10; ++i) {
            int cid = w * 10 + i;
            int jb  = cid & 3;
            int k10 = cid >> 2;
            glds16(qBb + ((size_t)jb * NKT + ph * 10 + k10) * CHUNK + lane * 8,
                   sbuf + cid * CHUNK + lane * 8);
        }
        __syncthreads();   // vmcnt(0) drain: B resident (2 drains/kernel total)

        int base = ph * 10;
        LOADA(a0, base)
#pragma unroll
        for (int k2 = 0; k2 < 10; k2 += 2) {
            BREAD(bb0, k2)
            LOADA(a1, base + k2 + 1)
            MFMASET(a0, bb0)
            BREAD(bb1, k2 + 1)
            if (k2 + 2 < 10) LOADA(a0, base + k2 + 2)
            MFMASET(a1, bb1)
        }
    }

    // ---- in-register top-3 over this wave's 112 rows, per owned column ----
    float T0[4], T1[4], T2[4];
#pragma unroll
    for (int j = 0; j < 4; ++j) { T0[j] = -1e30f; T1[j] = -1e30f; T2[j] = -1e30f; }
#pragma unroll
    for (int r = 0; r < 7; ++r)
#pragma unroll
        for (int j = 0; j < 4; ++j)
#pragma unroll
            for (int g = 0; g < 4; ++g) {
                int row = r * 64 + w * 16 + quad * 4 + g;   // C layout: row=quad*4+reg
                float v = (row < HW) ? acc[r][j][g] : -1e30f;
                ins3(T0[j], T1[j], T2[j], v);
            }

    // quad-butterfly merge (rows spread over lane bits 4,5)
#pragma unroll
    for (int j = 0; j < 4; ++j) {
#pragma unroll
        for (int d = 16; d <= 32; d <<= 1) {
            float o0 = __shfl_xor(T0[j], d, 64);
            float o1 = __shfl_xor(T1[j], d, 64);
            float o2 = __shfl_xor(T2[j], d, 64);
            ins3(T0[j], T1[j], T2[j], o0);
            ins3(T0[j], T1[j], T2[j], o1);
            ins3(T0[j], T1[j], T2[j], o2);
        }
    }

    // cross-wave merge via LDS
    if (quad == 0) {
#pragma unroll
        for (int j = 0; j < 4; ++j) {
            mrg[w][j * 16 + c16][0] = T0[j];
            mrg[w][j * 16 + c16][1] = T1[j];
            mrg[w][j * 16 + c16][2] = T2[j];
        }
    }
    __syncthreads();
    if (tid < 64) {
        int col = tid;
        float t0 = mrg[0][col][0], t1 = mrg[0][col][1], t2 = mrg[0][col][2];
#pragma unroll
        for (int ww = 1; ww < 4; ++ww) {
            ins3(t0, t1, t2, mrg[ww][col][0]);
            ins3(t0, t1, t2, mrg[ww][col][1]);
            ins3(t0, t1, t2, mrg[ww][col][2]);
        }
        float s = (mt * 64 + col < HW) ? (t0 + t1 + t2) : 0.f;
#pragma unroll
        for (int d = 32; d >= 1; d >>= 1) s += __shfl_xor(s, d, 64);
        if (tid == 0) atomicAdd(&out[b * N_CLS + n], s);
    }
}

extern "C" void kernel_launch(void* const* d_in, const int* in_sizes, int n_in,
                              void* d_out, int out_size, void* d_ws, size_t ws_size,
                              hipStream_t stream) {
    const float* q = (const float*)d_in[0];
    const float* S = (const float*)d_in[1];
    float* out = (float*)d_out;

    char* ws = (char*)d_ws;
    size_t off = 0;
    __hip_bfloat16* qn2 = (__hip_bfloat16*)(ws + off);
    off += (size_t)B_IMGS * NRB * NKT * CHUNK * 2;  off = (off + 255) & ~(size_t)255;
    __hip_bfloat16* sn2 = (__hip_bfloat16*)(ws + off);

    // 2 dispatches total: fused prep (also zeroes out) -> gemm
    prep_kernel<<<dim3(80 * 7), dim3(256), 0, stream>>>(q, S, qn2, sn2, out);
    // 8 XCD groups x 350 slots (35 blocks/image); b>=75 slots exit immediately
    gemm_top3_kernel<<<dim3(8 * 350), dim3(256), 0, stream>>>(qn2, sn2, out);
}